// Round 4
// baseline (436.617 us; speedup 1.0000x reference)
//
#include <hip/hip_runtime.h>
#include <math.h>

// Problem constants
#define NN    6272     // tokens per batch = 8*28*28
#define NBAT  2
#define CCH   512      // in channels
#define HCH   256      // hidden channels
#define SPLIT 4        // kv-split factor
#define NTS   49       // kv tiles (of 32) per split chunk: 4*49*32 = 6272

typedef float          f32x4 __attribute__((ext_vector_type(4)));
typedef unsigned int   u32x4 __attribute__((ext_vector_type(4)));
typedef _Float16       f16x8 __attribute__((ext_vector_type(8)));
typedef unsigned short u16x8 __attribute__((ext_vector_type(8)));
typedef unsigned short u16x4 __attribute__((ext_vector_type(4)));

// Scratch as device globals. ~95 MB total.
__device__ __attribute__((aligned(16))) unsigned short g_Xt[NBAT * NN * CCH]; // x transposed [n][m][c] fp16
__device__ __attribute__((aligned(16))) unsigned short g_Wq[HCH * CCH];       // w_theta fp16 [o][c]
__device__ __attribute__((aligned(16))) unsigned short g_Wk[HCH * CCH];       // w_phi
__device__ __attribute__((aligned(16))) unsigned short g_Wv[HCH * CCH];       // w_g
__device__ __attribute__((aligned(16))) unsigned short g_Wo[CCH * HCH];       // w_out [c][o]
__device__ __attribute__((aligned(16))) unsigned short g_Qg[NBAT * NN * HCH]; // theta [n][m][o]
__device__ __attribute__((aligned(16))) unsigned short g_Kg[NBAT * NN * HCH]; // phi   [n][kv][o]
__device__ __attribute__((aligned(16))) unsigned short g_Vt[NBAT * HCH * NN]; // g^T   [n][o][kv]
__device__ __attribute__((aligned(16))) unsigned short g_Yb[NBAT * NN * HCH]; // y     [n][m][o]
__device__ __attribute__((aligned(16))) float g_Yp[SPLIT * NBAT * NN * HCH];  // partial Y (unnormalized, f32)
__device__ __attribute__((aligned(16))) float g_Mp[SPLIT * NBAT * NN];        // partial running max
__device__ __attribute__((aligned(16))) float g_Lp[SPLIT * NBAT * NN];        // partial running sum

static __device__ __forceinline__ unsigned short f2h(float f) {
  _Float16 h = (_Float16)f;
  return __builtin_bit_cast(unsigned short, h);
}
static __device__ __forceinline__ f16x8 ldf(const unsigned short* p) {
  return __builtin_bit_cast(f16x8, *(const u32x4*)p);
}

// Light barrier: LDS visibility only (no vmcnt drain). vmem waits happen
// per-wave at the consuming commit, post-barrier, overlapped with other waves.
#define BAR() asm volatile("s_waitcnt lgkmcnt(0)\n\ts_barrier" ::: "memory")

// ---------------------------------------------------------------- weights
__global__ __launch_bounds__(256) void convw_kernel(const float* __restrict__ wt,
                                                    const float* __restrict__ wp,
                                                    const float* __restrict__ wg,
                                                    const float* __restrict__ wo) {
  int idx = blockIdx.x * 256 + threadIdx.x;   // 0 .. 524287
  int seg = idx >> 17;
  int off = idx & 131071;
  const float* s = (seg == 0) ? wt : (seg == 1) ? wp : (seg == 2) ? wg : wo;
  unsigned short* d = (seg == 0) ? g_Wq : (seg == 1) ? g_Wk : (seg == 2) ? g_Wv : g_Wo;
  d[off] = f2h(s[off]);
}

// ------------------------------------------------- x [n][c][m] -> Xt [n][m][c] fp16
// LDS tile u16[64 c][72 m-pad]. Read phase: lane owns column m = tid&63 so a
// wave's scalar reads span all 32 banks (bank = 8j + m mod 32) -> conflict-free.
__global__ __launch_bounds__(256) void transpose_kernel(const float* __restrict__ x) {
  __shared__ __attribute__((aligned(16))) unsigned short tile[64][72];
  const int tid = threadIdx.x;
  const int m0 = blockIdx.x * 64;
  const int c0 = blockIdx.y * 64;
  const int nb = blockIdx.z;
  const float* src = x + ((size_t)(nb * CCH + c0)) * NN + m0;
#pragma unroll
  for (int p = 0; p < 4; ++p) {
    int r  = p * 16 + (tid >> 4);
    int cc = (tid & 15) * 4;
    float4 v = *(const float4*)(src + (size_t)r * NN + cc);
    u16x4 h;
    h[0] = f2h(v.x); h[1] = f2h(v.y); h[2] = f2h(v.z); h[3] = f2h(v.w);
    *(u16x4*)&tile[r][cc] = h;
  }
  __syncthreads();
  unsigned short* dstbase = g_Xt + ((size_t)nb * NN + m0) * CCH + c0;
  const int m   = tid & 63;
  const int cgb = (tid >> 6) * 2;
#pragma unroll
  for (int p = 0; p < 2; ++p) {
    int cg = (cgb + p) * 8;
    u16x8 v;
#pragma unroll
    for (int j = 0; j < 8; ++j) v[j] = tile[cg + j][m];
    *(u16x8*)(dstbase + (size_t)m * CCH + cg) = v;
  }
}

// -------------------------------- theta/phi: out[m][o] = sum_c Xt[m][c] * W[o][c]
__global__ __launch_bounds__(256) void proj_qk_kernel() {
  const int tid  = threadIdx.x;
  const int lane = tid & 63;
  const int w    = tid >> 6;
  const int lo   = lane & 15, hi = lane >> 4;
  const int m0   = blockIdx.x * 64;
  const int nb   = blockIdx.y;
  const int which = blockIdx.z;
  const unsigned short* W  = which ? g_Wk : g_Wq;
  unsigned short*       dst = which ? g_Kg : g_Qg;

  const unsigned short* xrow = g_Xt + ((size_t)nb * NN + m0 + w * 16 + lo) * CCH + hi * 8;
  f32x4 acc[16];
#pragma unroll
  for (int i = 0; i < 16; ++i) acc[i] = (f32x4){0.f, 0.f, 0.f, 0.f};
  for (int ks = 0; ks < 16; ++ks) {
    f16x8 a = ldf(xrow + ks * 32);
#pragma unroll
    for (int of = 0; of < 16; ++of) {
      f16x8 b = ldf(W + (size_t)(of * 16 + lo) * CCH + ks * 32 + hi * 8);
      acc[of] = __builtin_amdgcn_mfma_f32_16x16x32_f16(a, b, acc[of], 0, 0, 0);
    }
  }
  unsigned short* drow = dst + ((size_t)nb * NN + m0 + w * 16 + hi * 4) * HCH + lo;
#pragma unroll
  for (int of = 0; of < 16; ++of)
#pragma unroll
    for (int r = 0; r < 4; ++r)
      drow[(size_t)r * HCH + of * 16] = f2h(acc[of][r]);
}

// -------------------------------- g^T: Vt[o][m] = sum_c Wv[o][c] * Xt[m][c]
__global__ __launch_bounds__(256) void vproj_kernel() {
  const int tid  = threadIdx.x;
  const int lane = tid & 63;
  const int w    = tid >> 6;
  const int lo   = lane & 15, hi = lane >> 4;
  const int m0   = blockIdx.x * 64;
  const int o0   = blockIdx.y * 64;
  const int nb   = blockIdx.z;
  const unsigned short* wrow = g_Wv + (size_t)(o0 + w * 16 + lo) * CCH + hi * 8;
  f32x4 acc[4];
#pragma unroll
  for (int i = 0; i < 4; ++i) acc[i] = (f32x4){0.f, 0.f, 0.f, 0.f};
  for (int ks = 0; ks < 16; ++ks) {
    f16x8 a = ldf(wrow + ks * 32);
#pragma unroll
    for (int mf = 0; mf < 4; ++mf) {
      f16x8 b = ldf(g_Xt + ((size_t)nb * NN + m0 + mf * 16 + lo) * CCH + ks * 32 + hi * 8);
      acc[mf] = __builtin_amdgcn_mfma_f32_16x16x32_f16(a, b, acc[mf], 0, 0, 0);
    }
  }
#pragma unroll
  for (int mf = 0; mf < 4; ++mf)
#pragma unroll
    for (int r = 0; r < 4; ++r)
      g_Vt[((size_t)nb * HCH + o0 + w * 16 + hi * 4 + r) * NN + m0 + mf * 16 + lo] = f2h(acc[mf][r]);
}

// -------------------------------- LDS-staged flash attention, kv-split
// 784 blocks; bid&7 -> (split,batch) XCD-affine; 4 waves x 16 m-rows.
// Per iter: issue K+V loads for t+1 at top (600-1000cy window), light barriers
// (lgkmcnt only), per-wave vmcnt waits at the post-barrier commits.
__global__ __launch_bounds__(256, 3) void attn_kernel() {
  __shared__ __attribute__((aligned(16))) unsigned short Klds[32][264];
  __shared__ __attribute__((aligned(16))) unsigned short Vlds[256][40];
  __shared__ __attribute__((aligned(16))) unsigned short Plds[64][40];

  const int tid  = threadIdx.x;
  const int lane = tid & 63;
  const int w    = tid >> 6;           // wave 0..3
  const int lo   = lane & 15, hi = lane >> 4;
  const int bid  = blockIdx.x;
  const int c    = bid & 7;
  const int sp   = c & 3;              // kv split chunk
  const int nb   = c >> 2;             // batch
  const int m0   = (bid >> 3) * 64;
  const int kv0  = sp * (NTS * 32);

  const unsigned short* Kb = g_Kg + (size_t)nb * NN * HCH;
  const unsigned short* Vb = g_Vt + (size_t)nb * HCH * NN;

  // staging roles (256 threads, 4 passes each of K and V)
  const int krow = tid >> 5;           // 0..7  (+ p*8)
  const int kcol = (tid & 31) * 8;
  const int vrow = tid >> 2;           // 0..63 (+ p*64)
  const int vcol = (tid & 3) * 8;
  u32x4 kreg[4], vreg[4];

  // Q fragments in registers: A[m][o], row = m0 + w*16 + lo
  u32x4 qf[8];
  {
    const unsigned short* qrow = g_Qg + ((size_t)nb * NN + m0 + w * 16 + lo) * HCH + hi * 8;
#pragma unroll
    for (int ks = 0; ks < 8; ++ks) qf[ks] = *(const u32x4*)(qrow + ks * 32);
  }

  f32x4 yacc[16];
#pragma unroll
  for (int i = 0; i < 16; ++i) yacc[i] = (f32x4){0.f, 0.f, 0.f, 0.f};
  float mrow[4] = {-3.0e38f, -3.0e38f, -3.0e38f, -3.0e38f};
  float lrow[4] = {0.f, 0.f, 0.f, 0.f};

  { // prologue: stage tile 0
    const unsigned short* ksrc = Kb + (size_t)(kv0 + krow) * HCH + kcol;
#pragma unroll
    for (int p = 0; p < 4; ++p) kreg[p] = *(const u32x4*)(ksrc + (size_t)p * 8 * HCH);
    const unsigned short* vsrc = Vb + (size_t)vrow * NN + kv0 + vcol;
#pragma unroll
    for (int p = 0; p < 4; ++p) vreg[p] = *(const u32x4*)(vsrc + (size_t)p * 64 * NN);
#pragma unroll
    for (int p = 0; p < 4; ++p) *(u32x4*)&Klds[p * 8 + krow][kcol] = kreg[p];
#pragma unroll
    for (int p = 0; p < 4; ++p) *(u32x4*)&Vlds[p * 64 + vrow][vcol] = vreg[p];
  }
  BAR();

  for (int t = 0; t < NTS; ++t) {
    const int  knext = kv0 + (t + 1) * 32;
    const bool more  = (t + 1 < NTS);
    // (A) issue K AND V loads for next tile
    if (more) {
      const unsigned short* ksrc = Kb + (size_t)(knext + krow) * HCH + kcol;
#pragma unroll
      for (int p = 0; p < 4; ++p) kreg[p] = *(const u32x4*)(ksrc + (size_t)p * 8 * HCH);
      const unsigned short* vsrc = Vb + (size_t)vrow * NN + knext + vcol;
#pragma unroll
      for (int p = 0; p < 4; ++p) vreg[p] = *(const u32x4*)(vsrc + (size_t)p * 64 * NN);
    }
    // (B) S = Q K^T
    f32x4 s0 = (f32x4){0.f, 0.f, 0.f, 0.f};
    f32x4 s1 = (f32x4){0.f, 0.f, 0.f, 0.f};
#pragma unroll
    for (int ks = 0; ks < 8; ++ks) {
      f16x8 b0 = ldf(&Klds[lo][ks * 32 + hi * 8]);
      f16x8 b1 = ldf(&Klds[16 + lo][ks * 32 + hi * 8]);
      f16x8 a  = __builtin_bit_cast(f16x8, qf[ks]);
      s0 = __builtin_amdgcn_mfma_f32_16x16x32_f16(a, b0, s0, 0, 0, 0);
      s1 = __builtin_amdgcn_mfma_f32_16x16x32_f16(a, b1, s1, 0, 0, 0);
    }
    // (C) online softmax with defer-max (THR=8): skip rescale when max growth small
    float sv0a[4], sv1a[4], mx[4];
#pragma unroll
    for (int r = 0; r < 4; ++r) {
      float sv0 = s0[r] * 16.0f, sv1 = s1[r] * 16.0f;  // pw *= sqrt(256)
      sv0a[r] = sv0; sv1a[r] = sv1;
      float m2 = fmaxf(sv0, sv1);
#pragma unroll
      for (int off = 8; off >= 1; off >>= 1) m2 = fmaxf(m2, __shfl_xor(m2, off));
      mx[r] = m2;
    }
    bool grow = (mx[0] > mrow[0] + 8.f) || (mx[1] > mrow[1] + 8.f) ||
                (mx[2] > mrow[2] + 8.f) || (mx[3] > mrow[3] + 8.f);
    if (__any((int)grow)) {
      float fac[4];
#pragma unroll
      for (int r = 0; r < 4; ++r) {
        float mnew = fmaxf(mrow[r], mx[r]);
        fac[r] = __expf(mrow[r] - mnew);
        mrow[r] = mnew;
        lrow[r] *= fac[r];
      }
#pragma unroll
      for (int of = 0; of < 16; ++of)
#pragma unroll
        for (int r = 0; r < 4; ++r) yacc[of][r] *= fac[r];
    }
#pragma unroll
    for (int r = 0; r < 4; ++r) {
      float p0 = __expf(sv0a[r] - mrow[r]);
      float p1 = __expf(sv1a[r] - mrow[r]);
      float rs = p0 + p1;
#pragma unroll
      for (int off = 8; off >= 1; off >>= 1) rs += __shfl_xor(rs, off);
      lrow[r] += rs;
      int prow = w * 16 + hi * 4 + r;
      Plds[prow][lo]      = f2h(p0);
      Plds[prow][16 + lo] = f2h(p1);
    }
    BAR();  // bar1: K reads + P writes retired (lgkm only, vmem stays in flight)
    // (D) commit next K tile (per-wave vmcnt wait lands here, post-barrier)
    if (more) {
#pragma unroll
      for (int p = 0; p < 4; ++p) *(u32x4*)&Klds[p * 8 + krow][kcol] = kreg[p];
    }
    // (E) Y += P V
    {
      f16x8 pa = ldf(&Plds[w * 16 + lo][hi * 8]);
#pragma unroll
      for (int of = 0; of < 16; ++of) {
        f16x8 b = ldf(&Vlds[of * 16 + lo][hi * 8]);
        yacc[of] = __builtin_amdgcn_mfma_f32_16x16x32_f16(pa, b, yacc[of], 0, 0, 0);
      }
    }
    BAR();  // bar2: V/P reads + K commit retired
    // (F) commit next V tile (vmcnt(0) per-wave, post-barrier)
    if (more) {
#pragma unroll
      for (int p = 0; p < 4; ++p) *(u32x4*)&Vlds[p * 64 + vrow][vcol] = vreg[p];
    }
  }
  // epilogue: unnormalized partial Y (f32) + running m, l
  {
    float* Yp = g_Yp + (((size_t)sp * NBAT + nb) * NN + m0 + w * 16 + hi * 4) * HCH + lo;
#pragma unroll
    for (int r = 0; r < 4; ++r)
#pragma unroll
      for (int of = 0; of < 16; ++of)
        Yp[(size_t)r * HCH + of * 16] = yacc[of][r];
    if (lo == 0) {
      size_t base = ((size_t)sp * NBAT + nb) * NN + m0 + w * 16 + hi * 4;
#pragma unroll
      for (int r = 0; r < 4; ++r) {
        g_Mp[base + r] = mrow[r];
        g_Lp[base + r] = lrow[r];
      }
    }
  }
}

// -------------------------------- combine kv-split partials -> g_Yb fp16
__global__ __launch_bounds__(256) void combine_kernel() {
  int gid = blockIdx.x * 256 + threadIdx.x;   // 0 .. 802815
  int og  = (gid & 63) * 4;
  int row = gid >> 6;                          // 0 .. 12543 (nb*NN + m)
  int nb  = (row >= NN) ? 1 : 0;
  int m   = row - nb * NN;

  float ms[SPLIT], ls[SPLIT];
#pragma unroll
  for (int s = 0; s < SPLIT; ++s) {
    size_t idx = ((size_t)s * NBAT + nb) * NN + m;
    ms[s] = g_Mp[idx];
    ls[s] = g_Lp[idx];
  }
  float M = ms[0];
#pragma unroll
  for (int s = 1; s < SPLIT; ++s) M = fmaxf(M, ms[s]);
  float wsc[SPLIT];
  float L = 0.f;
#pragma unroll
  for (int s = 0; s < SPLIT; ++s) { wsc[s] = __expf(ms[s] - M); L += wsc[s] * ls[s]; }
  f32x4 acc = (f32x4){0.f, 0.f, 0.f, 0.f};
#pragma unroll
  for (int s = 0; s < SPLIT; ++s) {
    f32x4 y = *(const f32x4*)&g_Yp[(((size_t)s * NBAT + nb) * NN + m) * HCH + og];
    acc += wsc[s] * y;
  }
  float inv = 1.0f / L;
  u16x4 outv;
#pragma unroll
  for (int j = 0; j < 4; ++j) outv[j] = f2h(acc[j] * inv);
  *(u16x4*)&g_Yb[((size_t)nb * NN + m) * HCH + og] = outv;
}

// -------------------------------- out[c][m] = x[c][m] + sum_o Wo[c][o] * y[m][o]
__global__ __launch_bounds__(256) void out_kernel(const float* __restrict__ x,
                                                  float* __restrict__ out) {
  const int tid  = threadIdx.x;
  const int lane = tid & 63;
  const int w    = tid >> 6;
  const int lo   = lane & 15, hi = lane >> 4;
  const int m0   = blockIdx.x * 64;
  const int c0   = blockIdx.y * 64;
  const int nb   = blockIdx.z;
  const unsigned short* wrow = g_Wo + (size_t)(c0 + w * 16 + lo) * HCH + hi * 8;
  f32x4 acc[4];
#pragma unroll
  for (int i = 0; i < 4; ++i) acc[i] = (f32x4){0.f, 0.f, 0.f, 0.f};
#pragma unroll
  for (int ks = 0; ks < 8; ++ks) {
    f16x8 a = ldf(wrow + ks * 32);
#pragma unroll
    for (int mf = 0; mf < 4; ++mf) {
      f16x8 b = ldf(g_Yb + ((size_t)nb * NN + m0 + mf * 16 + lo) * HCH + ks * 32 + hi * 8);
      acc[mf] = __builtin_amdgcn_mfma_f32_16x16x32_f16(a, b, acc[mf], 0, 0, 0);
    }
  }
#pragma unroll
  for (int mf = 0; mf < 4; ++mf)
#pragma unroll
    for (int r = 0; r < 4; ++r) {
      size_t idx = ((size_t)nb * CCH + c0 + w * 16 + hi * 4 + r) * NN + m0 + mf * 16 + lo;
      out[idx] = x[idx] + acc[mf][r];
    }
}

extern "C" void kernel_launch(void* const* d_in, const int* in_sizes, int n_in,
                              void* d_out, int out_size, void* d_ws, size_t ws_size,
                              hipStream_t stream) {
  const float* x  = (const float*)d_in[0];
  const float* wg = (const float*)d_in[1];  // V weight
  const float* wt = (const float*)d_in[2];  // Q weight (theta)
  const float* wp = (const float*)d_in[3];  // K weight (phi)
  const float* wo = (const float*)d_in[4];  // out weight
  float* out = (float*)d_out;
  (void)in_sizes; (void)n_in; (void)d_ws; (void)ws_size; (void)out_size;

  convw_kernel<<<2048, 256, 0, stream>>>(wt, wp, wg, wo);
  transpose_kernel<<<dim3(98, 8, NBAT), 256, 0, stream>>>(x);
  proj_qk_kernel<<<dim3(98, NBAT, 2), 256, 0, stream>>>();
  vproj_kernel<<<dim3(98, 4, NBAT), 256, 0, stream>>>();
  attn_kernel<<<784, 256, 0, stream>>>();
  combine_kernel<<<3136, 256, 0, stream>>>();
  out_kernel<<<dim3(98, 8, NBAT), 256, 0, stream>>>(x, out);
}

// Round 5
// 352.383 us; speedup vs baseline: 1.2390x; 1.2390x over previous
//
#include <hip/hip_runtime.h>
#include <math.h>

// Problem constants
#define NN    6272     // tokens per batch = 8*28*28
#define NBAT  2
#define CCH   512      // in channels
#define HCH   256      // hidden channels
#define SPLIT 4        // kv-split factor
#define NTS   49       // kv tiles (of 32) per split chunk: 4*49*32 = 6272

typedef float          f32x4  __attribute__((ext_vector_type(4)));
typedef float          f32x16 __attribute__((ext_vector_type(16)));
typedef unsigned int   u32x4  __attribute__((ext_vector_type(4)));
typedef _Float16       f16x8  __attribute__((ext_vector_type(8)));
typedef unsigned short u16x8  __attribute__((ext_vector_type(8)));
typedef unsigned short u16x4  __attribute__((ext_vector_type(4)));

// Scratch as device globals.
__device__ __attribute__((aligned(16))) unsigned short g_Xt[NBAT * NN * CCH]; // x^T [n][m][c] fp16
__device__ __attribute__((aligned(16))) unsigned short g_Wq[HCH * CCH];
__device__ __attribute__((aligned(16))) unsigned short g_Wk[HCH * CCH];
__device__ __attribute__((aligned(16))) unsigned short g_Wv[HCH * CCH];
__device__ __attribute__((aligned(16))) unsigned short g_Wo[CCH * HCH];
__device__ __attribute__((aligned(16))) unsigned short g_Qg[NBAT * NN * HCH]; // theta*16 [n][m][o]
__device__ __attribute__((aligned(16))) unsigned short g_Kg[NBAT * NN * HCH]; // phi [n][kv][o], o-chunks permuted: c^=kv&15
__device__ __attribute__((aligned(16))) unsigned short g_Vt[NBAT * HCH * NN]; // g^T [n][o][kv], kv-chunks(8) permuted per 32-blk: c^=o&3
__device__ __attribute__((aligned(16))) unsigned short g_Yb[NBAT * NN * HCH]; // y [n][m][o]
__device__ __attribute__((aligned(16))) float g_Yp[SPLIT * NBAT * HCH * NN];  // partial Y^T (unnormalized) [s][n][o][m]
__device__ __attribute__((aligned(16))) float g_Mp[SPLIT * NBAT * NN];
__device__ __attribute__((aligned(16))) float g_Lp[SPLIT * NBAT * NN];

static __device__ __forceinline__ unsigned short f2h(float f) {
  _Float16 h = (_Float16)f;
  return __builtin_bit_cast(unsigned short, h);
}
static __device__ __forceinline__ f16x8 ldf(const unsigned short* p) {
  return __builtin_bit_cast(f16x8, *(const u32x4*)p);
}

#define GL16(g, l) __builtin_amdgcn_global_load_lds(                                   \
    (const __attribute__((address_space(1))) void*)(g),                                \
    (__attribute__((address_space(3))) void*)(l), 16, 0, 0)

// ---------------------------------------------------------------- weights
__global__ __launch_bounds__(256) void convw_kernel(const float* __restrict__ wt,
                                                    const float* __restrict__ wp,
                                                    const float* __restrict__ wg,
                                                    const float* __restrict__ wo) {
  int idx = blockIdx.x * 256 + threadIdx.x;
  int seg = idx >> 17;
  int off = idx & 131071;
  const float* s = (seg == 0) ? wt : (seg == 1) ? wp : (seg == 2) ? wg : wo;
  unsigned short* d = (seg == 0) ? g_Wq : (seg == 1) ? g_Wk : (seg == 2) ? g_Wv : g_Wo;
  d[off] = f2h(s[off]);
}

// ------------------------------------------------- x [n][c][m] -> Xt [n][m][c] fp16
__global__ __launch_bounds__(256) void transpose_kernel(const float* __restrict__ x) {
  __shared__ __attribute__((aligned(16))) unsigned short tile[64][72];
  const int tid = threadIdx.x;
  const int m0 = blockIdx.x * 64;
  const int c0 = blockIdx.y * 64;
  const int nb = blockIdx.z;
  const float* src = x + ((size_t)(nb * CCH + c0)) * NN + m0;
#pragma unroll
  for (int p = 0; p < 4; ++p) {
    int r  = p * 16 + (tid >> 4);
    int cc = (tid & 15) * 4;
    float4 v = *(const float4*)(src + (size_t)r * NN + cc);
    u16x4 h;
    h[0] = f2h(v.x); h[1] = f2h(v.y); h[2] = f2h(v.z); h[3] = f2h(v.w);
    *(u16x4*)&tile[r][cc] = h;
  }
  __syncthreads();
  unsigned short* dstbase = g_Xt + ((size_t)nb * NN + m0) * CCH + c0;
  const int m   = tid & 63;
  const int cgb = (tid >> 6) * 2;
#pragma unroll
  for (int p = 0; p < 2; ++p) {
    int cg = (cgb + p) * 8;
    u16x8 v;
#pragma unroll
    for (int j = 0; j < 8; ++j) v[j] = tile[cg + j][m];
    *(u16x8*)(dstbase + (size_t)m * CCH + cg) = v;
  }
}

// -------------------------------- theta/phi projections.
// which==0 (Q): out scaled by 16 (folds sqrt(d)).  which==1 (K): o-chunk (16B=8 f16)
// index XORed with kv&15 (pre-swizzle for attn's conflict-free LDS reads).
__global__ __launch_bounds__(256) void proj_qk_kernel() {
  const int tid  = threadIdx.x;
  const int lane = tid & 63;
  const int w    = tid >> 6;
  const int lo   = lane & 15, hi = lane >> 4;
  const int m0   = blockIdx.x * 64;
  const int nb   = blockIdx.y;
  const int which = blockIdx.z;
  const unsigned short* W  = which ? g_Wk : g_Wq;
  unsigned short*      dst = which ? g_Kg : g_Qg;

  const unsigned short* xrow = g_Xt + ((size_t)nb * NN + m0 + w * 16 + lo) * CCH + hi * 8;
  f32x4 acc[16];
#pragma unroll
  for (int i = 0; i < 16; ++i) acc[i] = (f32x4){0.f, 0.f, 0.f, 0.f};
  for (int ks = 0; ks < 16; ++ks) {
    f16x8 a = ldf(xrow + ks * 32);
#pragma unroll
    for (int of = 0; of < 16; ++of) {
      f16x8 b = ldf(W + (size_t)(of * 16 + lo) * CCH + ks * 32 + hi * 8);
      acc[of] = __builtin_amdgcn_mfma_f32_16x16x32_f16(a, b, acc[of], 0, 0, 0);
    }
  }
  size_t rowbase = (size_t)nb * NN + m0 + w * 16 + hi * 4;
  if (which == 0) {
    unsigned short* drow = dst + rowbase * HCH + lo;
#pragma unroll
    for (int of = 0; of < 16; ++of)
#pragma unroll
      for (int r = 0; r < 4; ++r)
        drow[(size_t)r * HCH + of * 16] = f2h(acc[of][r] * 16.0f);
  } else {
#pragma unroll
    for (int of = 0; of < 16; ++of)
#pragma unroll
      for (int r = 0; r < 4; ++r) {
        int kvr = hi * 4 + r;                    // kv & 15
        int oc  = (of * 2 + (lo >> 3)) ^ kvr;    // permuted 16B-chunk index
        dst[(rowbase + r) * HCH + (oc << 3) + (lo & 7)] = f2h(acc[of][r]);
      }
  }
}

// -------------------------------- g^T: Vt[o][kv'] = sum_c Wv[o][c] * Xt[kv][c]
// kv-chunk (8 f16) within each 32-kv block permuted: c ^= o&3.
__global__ __launch_bounds__(256) void vproj_kernel() {
  const int tid  = threadIdx.x;
  const int lane = tid & 63;
  const int w    = tid >> 6;
  const int lo   = lane & 15, hi = lane >> 4;
  const int m0   = blockIdx.x * 64;
  const int o0   = blockIdx.y * 64;
  const int nb   = blockIdx.z;
  const unsigned short* wrow = g_Wv + (size_t)(o0 + w * 16 + lo) * CCH + hi * 8;
  f32x4 acc[4];
#pragma unroll
  for (int i = 0; i < 4; ++i) acc[i] = (f32x4){0.f, 0.f, 0.f, 0.f};
  for (int ks = 0; ks < 16; ++ks) {
    f16x8 a = ldf(wrow + ks * 32);
#pragma unroll
    for (int mf = 0; mf < 4; ++mf) {
      f16x8 b = ldf(g_Xt + ((size_t)nb * NN + m0 + mf * 16 + lo) * CCH + ks * 32 + hi * 8);
      acc[mf] = __builtin_amdgcn_mfma_f32_16x16x32_f16(a, b, acc[mf], 0, 0, 0);
    }
  }
#pragma unroll
  for (int mf = 0; mf < 4; ++mf)
#pragma unroll
    for (int r = 0; r < 4; ++r) {
      int o  = o0 + w * 16 + hi * 4 + r;
      int kv = m0 + mf * 16 + lo;
      int c  = ((kv & 31) >> 3) ^ (o & 3);       // permuted 8-elem chunk in 32-blk
      int kvp = (kv & ~31) | (c << 3) | (kv & 7);
      g_Vt[((size_t)nb * HCH + o) * NN + kvp] = f2h(acc[mf][r]);
    }
}

// -------------------------------- attention: 32x32x16 MFMA, swapped QK^T,
// in-register softmax+P, global_load_lds double-buffered K/V, 1 barrier/iter.
// Grid 392: bid&7 -> (split,batch) XCD-affine; bid>>3 -> m-tile of 128.
// 4 waves x 32 q-rows. Lane (lo5,hi1): owns q-row m=lo5 (col of S^T), 16 kv rows.
__global__ __launch_bounds__(256, 2) void attn_kernel() {
  __shared__ __attribute__((aligned(16))) unsigned short Kbuf[2][32 * 256];  // [kv][o] permuted
  __shared__ __attribute__((aligned(16))) unsigned short Vbuf[2][256 * 32];  // [o][kv] permuted

  const int tid  = threadIdx.x;
  const int wv   = tid >> 6;
  const int lane = tid & 63;
  const int lo5  = lane & 31, hi1 = lane >> 5;
  const int bid  = blockIdx.x;
  const int cmb  = bid & 7;
  const int sp   = cmb & 3;
  const int nb   = cmb >> 2;
  const int m0   = (bid >> 3) * 128;
  const int kv0  = sp * (NTS * 32);

  const unsigned short* Kb = g_Kg + (size_t)nb * NN * HCH;
  const unsigned short* Vb = g_Vt + (size_t)nb * HCH * NN;

  // Q B-frags: lane holds row m = m0+wv*32+lo5, 16B chunks at byte 32t+16*hi1
  u32x4 qf[16];
  {
    const unsigned short* qrow = g_Qg + ((size_t)nb * NN + m0 + wv * 32 + lo5) * HCH + hi1 * 8;
#pragma unroll
    for (int t = 0; t < 16; ++t) qf[t] = *(const u32x4*)(qrow + t * 16);
  }

  f32x16 yacc[8];
#pragma unroll
  for (int i = 0; i < 8; ++i) yacc[i] = (f32x16)(0.f);
  float mrow = -3.0e38f, lrow = 0.f;

  // staging: per thread 8x16B via global_load_lds (4 K passes + 4 V passes)
#define STAGE(buf, kvt)                                                                 \
  {                                                                                     \
    const unsigned short* ks_ = Kb + (size_t)(kvt) * HCH + tid * 8;                     \
    unsigned short* kd_ = &Kbuf[buf][tid * 8];                                          \
    GL16(ks_,          kd_);                                                            \
    GL16(ks_ + 2048,   kd_ + 2048);                                                     \
    GL16(ks_ + 4096,   kd_ + 4096);                                                     \
    GL16(ks_ + 6144,   kd_ + 6144);                                                     \
    _Pragma("unroll")                                                                   \
    for (int p_ = 0; p_ < 4; ++p_) {                                                    \
      int idx_ = p_ * 256 + tid;                                                        \
      const unsigned short* vs_ = Vb + (size_t)(idx_ >> 2) * NN + (kvt) + (idx_ & 3) * 8; \
      GL16(vs_, &Vbuf[buf][idx_ * 8]);                                                  \
    }                                                                                   \
  }

  STAGE(0, kv0);
  asm volatile("s_waitcnt vmcnt(0)" ::: "memory");
  __builtin_amdgcn_s_barrier();
  STAGE(1, kv0 + 32);
  int cur = 0;

  for (int t = 0; t < NTS; ++t) {
    const unsigned short* Kl = &Kbuf[cur][0];
    const unsigned short* Vl = &Vbuf[cur][0];
    // ---- S^T[kv][m] = K Q^T, two 8-deep chains
    f32x16 Sa = (f32x16)(0.f), Sb = (f32x16)(0.f);
#pragma unroll
    for (int tt = 0; tt < 8; ++tt) {
      f16x8 ka = ldf(Kl + lo5 * 256 + (((tt * 32 + hi1 * 16) ^ ((lo5 & 15) << 4)) >> 1));
      Sa = __builtin_amdgcn_mfma_f32_32x32x16_f16(ka, __builtin_bit_cast(f16x8, qf[tt]), Sa, 0, 0, 0);
    }
#pragma unroll
    for (int tt = 8; tt < 16; ++tt) {
      f16x8 ka = ldf(Kl + lo5 * 256 + (((tt * 32 + hi1 * 16) ^ ((lo5 & 15) << 4)) >> 1));
      Sb = __builtin_amdgcn_mfma_f32_32x32x16_f16(ka, __builtin_bit_cast(f16x8, qf[tt]), Sb, 0, 0, 0);
    }
    f32x16 S = Sa + Sb;
    // ---- online softmax, fully in-register (defer-max THR=8)
    float mx = S[0];
#pragma unroll
    for (int i = 1; i < 16; ++i) mx = fmaxf(mx, S[i]);
    mx = fmaxf(mx, __shfl_xor(mx, 32));
    if (!__all(mx <= mrow + 8.0f)) {
      float mnew = fmaxf(mrow, mx);
      float fac  = __expf(mrow - mnew);
      mrow = mnew;
      lrow *= fac;
#pragma unroll
      for (int of = 0; of < 8; ++of) yacc[of] *= fac;
    }
    float p[16];
#pragma unroll
    for (int i = 0; i < 16; ++i) p[i] = __expf(S[i] - mrow);
    float rs = ((p[0] + p[1]) + (p[2] + p[3])) + ((p[4] + p[5]) + (p[6] + p[7]))
             + ((p[8] + p[9]) + (p[10] + p[11])) + ((p[12] + p[13]) + (p[14] + p[15]));
    rs += __shfl_xor(rs, 32);
    lrow += rs;
    // ---- P -> B-frags (kv-step s: slot j = P^T[16s+8*hi1+j][m])
    u32x4 pf[2];
#pragma unroll
    for (int s = 0; s < 2; ++s) {
      unsigned int A0 = (unsigned int)f2h(p[8 * s + 0]) | ((unsigned int)f2h(p[8 * s + 1]) << 16);
      unsigned int A1 = (unsigned int)f2h(p[8 * s + 2]) | ((unsigned int)f2h(p[8 * s + 3]) << 16);
      unsigned int B0 = (unsigned int)f2h(p[8 * s + 4]) | ((unsigned int)f2h(p[8 * s + 5]) << 16);
      unsigned int B1 = (unsigned int)f2h(p[8 * s + 6]) | ((unsigned int)f2h(p[8 * s + 7]) << 16);
      unsigned int xA0 = (unsigned int)__shfl_xor((int)A0, 32);
      unsigned int xA1 = (unsigned int)__shfl_xor((int)A1, 32);
      unsigned int xB0 = (unsigned int)__shfl_xor((int)B0, 32);
      unsigned int xB1 = (unsigned int)__shfl_xor((int)B1, 32);
      pf[s][0] = hi1 ? xB0 : A0;
      pf[s][1] = hi1 ? xB1 : A1;
      pf[s][2] = hi1 ? B0 : xA0;
      pf[s][3] = hi1 ? B1 : xA1;
    }
    // ---- Y^T[o][m] += V P
#pragma unroll
    for (int of = 0; of < 8; ++of) {
#pragma unroll
      for (int s = 0; s < 2; ++s) {
        f16x8 va = ldf(Vl + (of * 32 + lo5) * 32 + (((s * 32 + hi1 * 16) ^ ((lo5 & 3) << 4)) >> 1));
        yacc[of] = __builtin_amdgcn_mfma_f32_32x32x16_f16(va, __builtin_bit_cast(f16x8, pf[s]), yacc[of], 0, 0, 0);
      }
    }
    // ---- advance pipeline
    if (t + 1 < NTS) {
      asm volatile("s_waitcnt vmcnt(0)\n\ts_barrier" ::: "memory");
      cur ^= 1;
      if (t + 2 < NTS) STAGE(cur ^ 1, kv0 + (t + 2) * 32);
    }
  }
#undef STAGE
  // epilogue: Y^T partial (f32) + m,l per q-row
  {
    const int m = m0 + wv * 32 + lo5;
    float* Yp = g_Yp + ((size_t)(sp * NBAT + nb) * HCH) * NN;
#pragma unroll
    for (int of = 0; of < 8; ++of)
#pragma unroll
      for (int reg = 0; reg < 16; ++reg) {
        int o = of * 32 + (reg & 3) + 8 * (reg >> 2) + 4 * hi1;
        Yp[(size_t)o * NN + m] = yacc[of][reg];
      }
    if (hi1 == 0) {
      size_t base = (size_t)(sp * NBAT + nb) * NN + m;
      g_Mp[base] = mrow;
      g_Lp[base] = lrow;
    }
  }
}

// -------------------------------- combine split partials (Y^T layout) -> g_Yb [m][o] fp16
__global__ __launch_bounds__(256) void combine_kernel() {
  __shared__ __attribute__((aligned(16))) float acc[64][68];
  __shared__ float wls[SPLIT][64];
  const int tid = threadIdx.x;
  const int m0 = blockIdx.x * 64, o0 = blockIdx.y * 64, nb = blockIdx.z;
  if (tid < 64) {
    int m = m0 + tid;
    float ms[SPLIT], ls[SPLIT];
#pragma unroll
    for (int s = 0; s < SPLIT; ++s) {
      size_t idx = (size_t)(s * NBAT + nb) * NN + m;
      ms[s] = g_Mp[idx];
      ls[s] = g_Lp[idx];
    }
    float M = ms[0];
#pragma unroll
    for (int s = 1; s < SPLIT; ++s) M = fmaxf(M, ms[s]);
    float L = 0.f, w[SPLIT];
#pragma unroll
    for (int s = 0; s < SPLIT; ++s) { w[s] = __expf(ms[s] - M); L += w[s] * ls[s]; }
    float inv = 1.0f / L;
#pragma unroll
    for (int s = 0; s < SPLIT; ++s) wls[s][tid] = w[s] * inv;
  }
  __syncthreads();
  {
    int ol = tid >> 2, mc = (tid & 3) * 16;
    f32x4 a[4] = {(f32x4)(0.f), (f32x4)(0.f), (f32x4)(0.f), (f32x4)(0.f)};
#pragma unroll
    for (int s = 0; s < SPLIT; ++s) {
      const float* src = g_Yp + ((size_t)(s * NBAT + nb) * HCH + o0 + ol) * NN + m0 + mc;
#pragma unroll
      for (int q = 0; q < 4; ++q) {
        f32x4 v = *(const f32x4*)(src + q * 4);
        f32x4 wv = *(const f32x4*)&wls[s][mc + q * 4];
        a[q] += wv * v;
      }
    }
#pragma unroll
    for (int q = 0; q < 4; ++q) *(f32x4*)&acc[ol][mc + q * 4] = a[q];
  }
  __syncthreads();
  {
    int ml = tid >> 2, oc = (tid & 3) * 16;
    u16x8 v0, v1;
#pragma unroll
    for (int j = 0; j < 8; ++j) { v0[j] = f2h(acc[oc + j][ml]); v1[j] = f2h(acc[oc + 8 + j][ml]); }
    unsigned short* dst = g_Yb + ((size_t)nb * NN + m0 + ml) * HCH + o0 + oc;
    *(u16x8*)dst = v0;
    *(u16x8*)(dst + 8) = v1;
  }
}

// -------------------------------- out[c][m] = x[c][m] + sum_o Wo[c][o] * y[m][o]
__global__ __launch_bounds__(256) void out_kernel(const float* __restrict__ x,
                                                  float* __restrict__ out) {
  const int tid  = threadIdx.x;
  const int lane = tid & 63;
  const int w    = tid >> 6;
  const int lo   = lane & 15, hi = lane >> 4;
  const int m0   = blockIdx.x * 64;
  const int c0   = blockIdx.y * 64;
  const int nb   = blockIdx.z;
  const unsigned short* wrow = g_Wo + (size_t)(c0 + w * 16 + lo) * HCH + hi * 8;
  f32x4 acc[4];
#pragma unroll
  for (int i = 0; i < 4; ++i) acc[i] = (f32x4){0.f, 0.f, 0.f, 0.f};
#pragma unroll
  for (int ks = 0; ks < 8; ++ks) {
    f16x8 a = ldf(wrow + ks * 32);
#pragma unroll
    for (int mf = 0; mf < 4; ++mf) {
      f16x8 b = ldf(g_Yb + ((size_t)nb * NN + m0 + mf * 16 + lo) * HCH + ks * 32 + hi * 8);
      acc[mf] = __builtin_amdgcn_mfma_f32_16x16x32_f16(a, b, acc[mf], 0, 0, 0);
    }
  }
#pragma unroll
  for (int mf = 0; mf < 4; ++mf)
#pragma unroll
    for (int r = 0; r < 4; ++r) {
      size_t idx = ((size_t)nb * CCH + c0 + w * 16 + hi * 4 + r) * NN + m0 + mf * 16 + lo;
      out[idx] = x[idx] + acc[mf][r];
    }
}

extern "C" void kernel_launch(void* const* d_in, const int* in_sizes, int n_in,
                              void* d_out, int out_size, void* d_ws, size_t ws_size,
                              hipStream_t stream) {
  const float* x  = (const float*)d_in[0];
  const float* wg = (const float*)d_in[1];  // V weight
  const float* wt = (const float*)d_in[2];  // Q weight (theta)
  const float* wp = (const float*)d_in[3];  // K weight (phi)
  const float* wo = (const float*)d_in[4];  // out weight
  float* out = (float*)d_out;
  (void)in_sizes; (void)n_in; (void)d_ws; (void)ws_size; (void)out_size;

  convw_kernel<<<2048, 256, 0, stream>>>(wt, wp, wg, wo);
  transpose_kernel<<<dim3(98, 8, NBAT), 256, 0, stream>>>(x);
  proj_qk_kernel<<<dim3(98, NBAT, 2), 256, 0, stream>>>();
  vproj_kernel<<<dim3(98, 4, NBAT), 256, 0, stream>>>();
  attn_kernel<<<392, 256, 0, stream>>>();
  combine_kernel<<<dim3(98, 4, NBAT), 256, 0, stream>>>();
  out_kernel<<<dim3(98, 8, NBAT), 256, 0, stream>>>(x, out);
}